// Round 13
// baseline (190.882 us; speedup 1.0000x reference)
//
#include <hip/hip_runtime.h>
#include <hip/hip_bf16.h>

// LSTM cell fused kernel for MI355X (gfx950) — round 13: 128-tile, 3 blocks/CU.
// stacked = [x|prevh] @ [Wx;Wh] + bx -> gates -> nexth, nextc
// GEMM: M=8192, N=4096 (4 gates x 1024 states), K=2048, bf16 16x16x32 MFMA.
//
// Thesis: all 256^2 rounds ran 1 block/CU (128KB LDS) — every barrier/wait
// idled the CU (MfmaUtil pinned ~33%). Guide tile table: 2-barrier structures
// peak at 128^2 with ~3 blocks/CU (cross-block TLP covers stalls, m114).
// r9 tested this with broken register math (spill); this round: acc=64 AGPR,
// 32KB LDS, launch_bounds(256,3) -> 3 resident blocks, no spill.
//
// Geometry: tile 128 rows x 128 n'-cols (=32 states x 4 gates), BK=32,
// 4 waves 2Mx2N, per-wave 64x64. Grid 2048 (64 Mt x 32 Nt), XCD-chunked.
//
// LDS (32KB): A dbuf 2x8KB [0,16K), B dbuf [16K,32K). PAIRED-ROW layout:
// LDS row R (128B) holds logical rows {2R, 2R+1} (64B of k each). This makes
// rows 128B => identical bank geometry + XOR swizzle to r3-r6 (measured 0
// conflicts). Decode: phys (R, gp): glog = gp ^ (R&7); logical row = 2R +
// (glog>>2), k_elem = (glog&3)*8.
//   staging (linear gload_lds dest, o = r*4096 + w*1024 + lane*16):
//     R = r*32 + w*8 + (lane>>3); gp = lane&7; glog = gp ^ (lane>>3)
//     src row = 2R + (glog>>2), k = t*32 + (glog&3)*8   [inverse-swizzled]
//   read af[m] (logical lr = wr*64+m*16+l15, q = lane>>4):
//     R = lr>>1; glog = (lr&1)*4 + q; gp = glog ^ (l15>>1)
//     addr = (wr*32+m*8)*128 + rdoff,  rdoff = (l15>>1)*128 + gp*16 (lane-const)
//
// Per tile t (64 tiles): {8 ds_read_b128; stage(t+1) 4 gloads; lgkm(0);
// 16 indep MFMA; vmcnt(0); barrier}. RAW: buf[t&1] staged at t-1, confirmed
// by t-1's vmcnt(0)+barrier. WAR: stage(t+1) writes opposite buffer. The
// exposed waits are covered by the other 2 resident blocks (the thesis).
//
// Gate fusion: Wt permuted n' = (s>>4)*64 + g*16 + (s&15); wave wc owns
// 16 states x 4 gates -> lane-local epilogue. ws: A bf16 32MB | Wt 16MB.

#define BATCH   8192
#define SDIM    1024
#define KDIM    2048
#define NT      64      // K-tiles of 32

typedef __attribute__((ext_vector_type(8))) short s16x8;
typedef __attribute__((ext_vector_type(4))) float f32x4;

__device__ __forceinline__ void gload16(const void* g, void* l) {
    __builtin_amdgcn_global_load_lds((const __attribute__((address_space(1))) void*)g,
                                     (__attribute__((address_space(3))) void*)l,
                                     16, 0, 0);
}

__device__ __forceinline__ float fast_sigmoid(float x) {
    return 1.0f / (1.0f + __expf(-x));
}
__device__ __forceinline__ float fast_tanh(float v) {
    float a = fabsf(v);
    float e = __expf(-2.0f * a);
    float t = (1.0f - e) / (1.0f + e);
    return copysignf(t, v);
}

// ---------------- merged conversions (r11, neutral-verified) -----------------
__global__ __launch_bounds__(256) void convAW(
    const float* __restrict__ x,  const float* __restrict__ h,
    const float* __restrict__ Wx, const float* __restrict__ Wh,
    __hip_bfloat16* __restrict__ A, __hip_bfloat16* __restrict__ Wt)
{
    __shared__ float tile[64][68];
    if (blockIdx.x < 8192) {
        int t = blockIdx.x * 256 + threadIdx.x;
        int e = t << 3;
        int b = e >> 11;
        int k = e & 2047;
        const float* src = (k < 1024) ? (x + (size_t)b * 1024 + k)
                                      : (h + (size_t)b * 1024 + (k - 1024));
        float4 v0 = *(const float4*)(src);
        float4 v1 = *(const float4*)(src + 4);
        union { __hip_bfloat16 b[8]; s16x8 v; } u;
        u.b[0] = __float2bfloat16(v0.x); u.b[1] = __float2bfloat16(v0.y);
        u.b[2] = __float2bfloat16(v0.z); u.b[3] = __float2bfloat16(v0.w);
        u.b[4] = __float2bfloat16(v1.x); u.b[5] = __float2bfloat16(v1.y);
        u.b[6] = __float2bfloat16(v1.z); u.b[7] = __float2bfloat16(v1.w);
        *(s16x8*)(A + e) = u.v;
    } else {
        const int wb = blockIdx.x - 8192;   // 0..2047
        const int kt = wb & 31;
        const int nt = wb >> 5;
        const int k0 = kt * 64, n0 = nt * 64;
        const int t  = threadIdx.x;
        {
            int r = t >> 2;
            int c = (t & 3) * 16;
            int k = k0 + r;
            const float* src = (k < 1024) ? (Wx + (size_t)k * 4096 + n0 + c)
                                          : (Wh + (size_t)(k - 1024) * 4096 + n0 + c);
#pragma unroll
            for (int jq = 0; jq < 4; ++jq)
                *(float4*)&tile[r][c + jq * 4] = *(const float4*)(src + jq * 4);
        }
        __syncthreads();
#pragma unroll
        for (int it = 0; it < 2; ++it) {
            int item = t + it * 256;
            int oct  = item >> 6;
            int nl   = item & 63;
            int n    = n0 + nl;
            int s    = n & 1023, g = n >> 10;
            int np   = (s >> 4) * 64 + g * 16 + (s & 15);
            union { __hip_bfloat16 b[8]; s16x8 v; } u;
#pragma unroll
            for (int e = 0; e < 8; ++e)
                u.b[e] = __float2bfloat16(tile[oct * 8 + e][nl]);
            *(s16x8*)(Wt + (size_t)np * 2048 + k0 + oct * 8) = u.v;
        }
    }
}

// ---------------- fused GEMM + gates (128-tile, 3 blocks/CU) ----------------
__global__ __launch_bounds__(256, 3) void lstm_gemm(
    const __hip_bfloat16* __restrict__ A,    // [8192][2048]
    const __hip_bfloat16* __restrict__ Wt,   // [4096 perm][2048]
    const float* __restrict__ bx,            // [4096]
    const float* __restrict__ prevc,         // [8192][1024]
    float* __restrict__ outh,
    float* __restrict__ outc)
{
    __shared__ __align__(16) char lds[32768];

    const int tid  = threadIdx.x;
    const int lane = tid & 63;
    const int w    = tid >> 6;   // 0..3
    const int wr   = w >> 1;     // 0..1  M half (64 rows)
    const int wc   = w & 1;      // 0..1  N half (64 n'-cols)
    const int l15  = lane & 15;

    // XCD chunking: 8 chunks of 16Mt x 16Nt (grid 2048 = 64Mt x 32Nt).
    const int bid = blockIdx.x;
    const int xcd = bid & 7, j = bid >> 3;          // j 0..255
    const int mt  = (xcd >> 1) * 16 + (j & 15);     // 0..63
    const int ntl = (xcd & 1) * 16 + (j >> 4);      // 0..31
    const int m0  = mt * 128, n0 = ntl * 128;

    // staging decode (see header): glog = (lane&7) ^ (lane>>3)
    const int gl    = (lane & 7) ^ (lane >> 3);
    const int gl_hi = gl >> 2;             // logical row parity add
    const int gl_k  = (gl & 3) * 8;        // k elems
    const __hip_bfloat16* Ag = A  + (size_t)m0 * KDIM;
    const __hip_bfloat16* Bg = Wt + (size_t)n0 * KDIM;

    auto SA = [&](int tt) {
        char* dst = lds + (tt & 1) * 8192 + w * 1024;
#pragma unroll
        for (int r = 0; r < 2; ++r) {
            int row = 2 * (r * 32 + w * 8 + (lane >> 3)) + gl_hi;
            gload16(Ag + (size_t)row * KDIM + tt * 32 + gl_k, dst + r * 4096);
        }
    };
    auto SB = [&](int tt) {
        char* dst = lds + 16384 + (tt & 1) * 8192 + w * 1024;
#pragma unroll
        for (int r = 0; r < 2; ++r) {
            int row = 2 * (r * 32 + w * 8 + (lane >> 3)) + gl_hi;
            gload16(Bg + (size_t)row * KDIM + tt * 32 + gl_k, dst + r * 4096);
        }
    };

    f32x4 acc[4][4];   // [m_frag][gate] — 64 AGPR
#pragma unroll
    for (int m = 0; m < 4; ++m)
#pragma unroll
        for (int g = 0; g < 4; ++g)
            acc[m][g] = (f32x4)0.0f;

    // prologue
    SA(0); SB(0);
    asm volatile("s_waitcnt vmcnt(0)" ::: "memory");
    __builtin_amdgcn_s_barrier();
    __builtin_amdgcn_sched_barrier(0);

    // read offsets (lane-constant): rdoff = (l15>>1)*128 + gp*16,
    // gp = ((l15&1)*4 + (lane>>4)) ^ (l15>>1)
    const int rdoff = ((l15 >> 1) << 7)
                    + (((((l15 & 1) << 2) | (lane >> 4)) ^ (l15 >> 1)) << 4);
    const int abase = wr * 32 * 128;   // + m*8*128
    const int bbase = wc * 32 * 128;   // + g*8*128

    s16x8 af[4], bf[4];

    for (int t = 0; t < NT; ++t) {
        const char* as = lds + (t & 1) * 8192;
        const char* bs = lds + 16384 + (t & 1) * 8192;

#pragma unroll
        for (int g = 0; g < 4; ++g)
            bf[g] = *(const s16x8*)(bs + bbase + g * 1024 + rdoff);
#pragma unroll
        for (int m = 0; m < 4; ++m)
            af[m] = *(const s16x8*)(as + abase + m * 1024 + rdoff);

        if (t + 1 < NT) { SA(t + 1); SB(t + 1); }

        asm volatile("s_waitcnt lgkmcnt(0)" ::: "memory");
        __builtin_amdgcn_sched_barrier(0);
        __builtin_amdgcn_s_setprio(1);
#pragma unroll
        for (int m = 0; m < 4; ++m)
#pragma unroll
            for (int g = 0; g < 4; ++g)
                acc[m][g] = __builtin_amdgcn_mfma_f32_16x16x32_bf16(
                    af[m], bf[g], acc[m][g], 0, 0, 0);
        __builtin_amdgcn_s_setprio(0);

        asm volatile("s_waitcnt vmcnt(0)" ::: "memory");
        __builtin_amdgcn_s_barrier();
        __builtin_amdgcn_sched_barrier(0);
    }

    // ---- fused epilogue: 4 gates lane-local ----
    const int st  = ntl * 32 + wc * 16 + l15;
    const float b_i = bx[st];
    const float b_f = bx[1024 + st];
    const float b_o = bx[2048 + st];
    const float b_g = bx[3072 + st];
    const int rbase = m0 + wr * 64 + (lane >> 4) * 4;

#pragma unroll
    for (int m = 0; m < 4; ++m) {
#pragma unroll
        for (int q = 0; q < 4; ++q) {
            int row = rbase + m * 16 + q;
            float ib = acc[m][0][q] + b_i;
            float fb = acc[m][1][q] + b_f;
            float ob = acc[m][2][q] + b_o;
            float gb = acc[m][3][q] + b_g;
            float ig = fast_sigmoid(ib);
            float fg = fast_sigmoid(fb);
            float og = fast_sigmoid(ob);
            float gg = fast_tanh(gb);
            float pc = prevc[(size_t)row * SDIM + st];
            float nc = pc * fg + gg * ig;
            float nh = fast_tanh(nc) * og;
            outh[(size_t)row * SDIM + st] = nh;
            outc[(size_t)row * SDIM + st] = nc;
        }
    }
}

extern "C" void kernel_launch(void* const* d_in, const int* in_sizes, int n_in,
                              void* d_out, int out_size, void* d_ws, size_t ws_size,
                              hipStream_t stream) {
    const float* x     = (const float*)d_in[0];
    const float* prevh = (const float*)d_in[1];
    const float* prevc = (const float*)d_in[2];
    const float* Wx    = (const float*)d_in[3];
    const float* bx    = (const float*)d_in[4];
    const float* Wh    = (const float*)d_in[5];

    __hip_bfloat16* Abf = (__hip_bfloat16*)d_ws;
    __hip_bfloat16* Wt  = Abf + (size_t)BATCH * KDIM;   // +32MB

    float* outh = (float*)d_out;
    float* outc = outh + (size_t)BATCH * SDIM;

    hipLaunchKernelGGL(convAW, dim3(10240), dim3(256), 0, stream,
                       x, prevh, Wx, Wh, Abf, Wt);
    // 64 Mtiles x 32 Ntiles = 2048 blocks
    hipLaunchKernelGGL(lstm_gemm, dim3(2048), dim3(256), 0, stream,
                       Abf, Wt, bx, prevc, outh, outc);
}

// Round 14
// 155.941 us; speedup vs baseline: 1.2241x; 1.2241x over previous
//
#include <hip/hip_runtime.h>
#include <hip/hip_bf16.h>

// LSTM cell fused kernel for MI355X (gfx950) — round 14: REVERT to round 11
// (best measured: 156.34 µs). convAW merged conversions + round-4 GEMM.
//
// stacked = [x|prevh] @ [Wx;Wh] + bx -> gates -> nexth, nextc
// GEMM: M=8192, N=4096 (4 gates x 1024 states), K=2048, bf16 16x16x32 MFMA.
//
// Session conclusion encoded here: 8 structural axes (phases, barriers,
// vmcnt depth, MFMA order, swizzle, B-path, MFMA shape, occupancy) all
// leave MfmaUtil at 30-33% — this staged-GEMM family plateaus at ~42% of
// dense peak in plain HIP on this chip; conversions are BW-bound.
//
// ws layout: A_bf16 [8192][2048] (32MB) | Wt_bf16 [4096 perm][2048] (16MB)

#define BATCH   8192
#define SDIM    1024
#define KDIM    2048
#define NT      32      // K-tiles of 64

typedef __attribute__((ext_vector_type(8))) short s16x8;
typedef __attribute__((ext_vector_type(4))) float f32x4;

__device__ __forceinline__ void gload16(const void* g, void* l) {
    __builtin_amdgcn_global_load_lds((const __attribute__((address_space(1))) void*)g,
                                     (__attribute__((address_space(3))) void*)l,
                                     16, 0, 0);
}

__device__ __forceinline__ float fast_sigmoid(float x) {
    return 1.0f / (1.0f + __expf(-x));
}
__device__ __forceinline__ float fast_tanh(float v) {
    float a = fabsf(v);
    float e = __expf(-2.0f * a);
    float t = (1.0f - e) / (1.0f + e);
    return copysignf(t, v);
}

// ---------------- merged conversions ----------------------------------------
// blocks [0, 8192):  A = [x | prevh] -> bf16 [8192][2048]   (16B loads/stores)
// blocks [8192, 10240): Wt[np][k] = W[k][n], np = (s>>4)*64 + g*16 + (s&15)
//   via 64k x 64n LDS transpose tile; 16B (8-k-run) stores.
__global__ __launch_bounds__(256) void convAW(
    const float* __restrict__ x,  const float* __restrict__ h,
    const float* __restrict__ Wx, const float* __restrict__ Wh,
    __hip_bfloat16* __restrict__ A, __hip_bfloat16* __restrict__ Wt)
{
    __shared__ float tile[64][68];
    if (blockIdx.x < 8192) {
        int t = blockIdx.x * 256 + threadIdx.x;
        int e = t << 3;
        int b = e >> 11;
        int k = e & 2047;
        const float* src = (k < 1024) ? (x + (size_t)b * 1024 + k)
                                      : (h + (size_t)b * 1024 + (k - 1024));
        float4 v0 = *(const float4*)(src);
        float4 v1 = *(const float4*)(src + 4);
        union { __hip_bfloat16 b[8]; s16x8 v; } u;
        u.b[0] = __float2bfloat16(v0.x); u.b[1] = __float2bfloat16(v0.y);
        u.b[2] = __float2bfloat16(v0.z); u.b[3] = __float2bfloat16(v0.w);
        u.b[4] = __float2bfloat16(v1.x); u.b[5] = __float2bfloat16(v1.y);
        u.b[6] = __float2bfloat16(v1.z); u.b[7] = __float2bfloat16(v1.w);
        *(s16x8*)(A + e) = u.v;
    } else {
        const int wb = blockIdx.x - 8192;   // 0..2047
        const int kt = wb & 31;             // 32 k-tiles of 64
        const int nt = wb >> 5;             // 64 n-tiles of 64
        const int k0 = kt * 64, n0 = nt * 64;
        const int t  = threadIdx.x;

        {
            int r = t >> 2;
            int c = (t & 3) * 16;
            int k = k0 + r;   // k0 is 64-aligned: row never straddles Wx/Wh
            const float* src = (k < 1024) ? (Wx + (size_t)k * 4096 + n0 + c)
                                          : (Wh + (size_t)(k - 1024) * 4096 + n0 + c);
#pragma unroll
            for (int jq = 0; jq < 4; ++jq)
                *(float4*)&tile[r][c + jq * 4] = *(const float4*)(src + jq * 4);
        }
        __syncthreads();

#pragma unroll
        for (int it = 0; it < 2; ++it) {
            int item = t + it * 256;
            int oct  = item >> 6;          // 0..7
            int nl   = item & 63;
            int n    = n0 + nl;
            int s    = n & 1023, g = n >> 10;
            int np   = (s >> 4) * 64 + g * 16 + (s & 15);
            union { __hip_bfloat16 b[8]; s16x8 v; } u;
#pragma unroll
            for (int e = 0; e < 8; ++e)
                u.b[e] = __float2bfloat16(tile[oct * 8 + e][nl]);
            *(s16x8*)(Wt + (size_t)np * 2048 + k0 + oct * 8) = u.v;
        }
    }
}

// ---------------- fused GEMM + gates (round-4 schedule) ---------------------
// 256x256 tile, BK=64, 8 waves (2M x 4N); A ring 4 half-slots [0,64K),
// B ring [64K,128K), half (t,p) at slot 2*(t&1)+p. 2 barriers/tile:
//   region1: bf reads(8) + af-lo reads(8) + SA(t+1)x2; 32 MFMA kf-outer
//   mid-barrier (B(t) LDS reads retired)
//   region2: af-hi reads(8, reuse regs) + SB(t+2)x2; 32 MFMA; vmcnt(4); bar
// T2 swizzle both-sides (0 conflicts measured), XCD chunking,
// gate-permuted Wt -> lane-local epilogue.
__global__ __launch_bounds__(512, 2) void lstm_gemm(
    const __hip_bfloat16* __restrict__ A,    // [8192][2048]
    const __hip_bfloat16* __restrict__ Wt,   // [4096 perm][2048]
    const float* __restrict__ bx,            // [4096]
    const float* __restrict__ prevc,         // [8192][1024]
    float* __restrict__ outh,
    float* __restrict__ outc)
{
    __shared__ __align__(16) char lds[131072];

    const int tid  = threadIdx.x;
    const int lane = tid & 63;
    const int w    = tid >> 6;   // 0..7
    const int wr   = w >> 2;     // 0..1  A-half
    const int wc   = w & 3;      // 0..3  N quarter; B-half = wc>>1
    const int l15  = lane & 15;

    const int bid = blockIdx.x;
    const int xcd = bid & 7, j = bid >> 3;
    const int mt = (xcd >> 1) * 8 + (j & 7);     // 0..31
    const int nt = (xcd & 1) * 8 + (j >> 3);     // 0..15
    const int m0 = mt * 256, n0 = nt * 256, S0 = nt * 64;

    const int scol = ((lane & 7) ^ (lane >> 3)) << 3;   // elems
    const __hip_bfloat16* Ag = A  + (size_t)m0 * KDIM;
    const __hip_bfloat16* Bg = Wt + (size_t)n0 * KDIM;

    auto SA = [&](int tt, int p) {
        char* dst = lds + (2 * (tt & 1) + p) * 16384 + w * 1024;
        const __hip_bfloat16* src =
            Ag + (size_t)(p * 128 + w * 8 + (lane >> 3)) * KDIM + tt * 64 + scol;
        gload16(src, dst);
        gload16(src + (size_t)64 * KDIM, dst + 8192);
    };
    auto SB = [&](int tt, int p) {
        char* dst = lds + 65536 + (2 * (tt & 1) + p) * 16384 + w * 1024;
        const __hip_bfloat16* src =
            Bg + (size_t)(p * 128 + w * 8 + (lane >> 3)) * KDIM + tt * 64 + scol;
        gload16(src, dst);
        gload16(src + (size_t)64 * KDIM, dst + 8192);
    };

    f32x4 acc[8][4];
#pragma unroll
    for (int m = 0; m < 8; ++m)
#pragma unroll
        for (int g = 0; g < 4; ++g)
            acc[m][g] = (f32x4)0.0f;

    SB(0, 0); SB(0, 1); SA(0, 0); SA(0, 1); SB(1, 0); SB(1, 1);
    asm volatile("s_waitcnt vmcnt(4)" ::: "memory");
    __builtin_amdgcn_s_barrier();
    __builtin_amdgcn_sched_barrier(0);

    const int swz0 = (((lane >> 4))     ^ (lane & 7)) << 4;
    const int swz1 = (((lane >> 4) | 4) ^ (lane & 7)) << 4;
    const int brow = (wc & 1) * 64;

    s16x8 af[4][2], bf[4][2];

    for (int t = 0; t < NT; ++t) {
        const char* as = lds + (2 * (t & 1) + wr) * 16384;
        const char* bs = lds + 65536 + (2 * (t & 1) + (wc >> 1)) * 16384;

        // ---- region 1: B reads, A-lo reads, SA(t+1); MFMA m0-3 x g0-3 ----
#pragma unroll
        for (int g = 0; g < 4; ++g) {
            bf[g][0] = *(const s16x8*)(bs + (brow + g * 16 + l15) * 128 + swz0);
            bf[g][1] = *(const s16x8*)(bs + (brow + g * 16 + l15) * 128 + swz1);
        }
#pragma unroll
        for (int m = 0; m < 4; ++m) {
            af[m][0] = *(const s16x8*)(as + (m * 16 + l15) * 128 + swz0);
            af[m][1] = *(const s16x8*)(as + (m * 16 + l15) * 128 + swz1);
        }
        if (t + 1 < NT) { SA(t + 1, 0); SA(t + 1, 1); }

        __builtin_amdgcn_s_setprio(1);
#pragma unroll
        for (int kf = 0; kf < 2; ++kf)
#pragma unroll
            for (int m = 0; m < 4; ++m)
#pragma unroll
                for (int g = 0; g < 4; ++g)
                    acc[m][g] = __builtin_amdgcn_mfma_f32_16x16x32_bf16(
                        af[m][kf], bf[g][kf], acc[m][g], 0, 0, 0);
        __builtin_amdgcn_s_setprio(0);

        __builtin_amdgcn_sched_barrier(0);
        __builtin_amdgcn_s_barrier();        // mid: all B(t) reads retired
        __builtin_amdgcn_sched_barrier(0);

        // ---- region 2: A-hi reads (reuse af), SB(t+2); MFMA m4-7 x g0-3 ----
#pragma unroll
        for (int m = 0; m < 4; ++m) {
            af[m][0] = *(const s16x8*)(as + ((m + 4) * 16 + l15) * 128 + swz0);
            af[m][1] = *(const s16x8*)(as + ((m + 4) * 16 + l15) * 128 + swz1);
        }
        if (t + 2 < NT) { SB(t + 2, 0); SB(t + 2, 1); }

        __builtin_amdgcn_s_setprio(1);
#pragma unroll
        for (int kf = 0; kf < 2; ++kf)
#pragma unroll
            for (int m = 0; m < 4; ++m)
#pragma unroll
                for (int g = 0; g < 4; ++g)
                    acc[m + 4][g] = __builtin_amdgcn_mfma_f32_16x16x32_bf16(
                        af[m][kf], bf[g][kf], acc[m + 4][g], 0, 0, 0);
        __builtin_amdgcn_s_setprio(0);

        __builtin_amdgcn_sched_barrier(0);
        if (t + 2 < NT) {
            asm volatile("s_waitcnt vmcnt(4)" ::: "memory");
        } else {
            asm volatile("s_waitcnt vmcnt(0)" ::: "memory");
        }
        __builtin_amdgcn_s_barrier();        // end: tile t+1 slots published
        __builtin_amdgcn_sched_barrier(0);
    }

    // ---- fused epilogue: 4 gates lane-local ----
    const int st  = S0 + wc * 16 + l15;
    const float b_i = bx[st];
    const float b_f = bx[1024 + st];
    const float b_o = bx[2048 + st];
    const float b_g = bx[3072 + st];
    const int rbase = m0 + wr * 128 + (lane >> 4) * 4;

#pragma unroll
    for (int m = 0; m < 8; ++m) {
#pragma unroll
        for (int q = 0; q < 4; ++q) {
            int row = rbase + m * 16 + q;
            float ib = acc[m][0][q] + b_i;
            float fb = acc[m][1][q] + b_f;
            float ob = acc[m][2][q] + b_o;
            float gb = acc[m][3][q] + b_g;
            float ig = fast_sigmoid(ib);
            float fg = fast_sigmoid(fb);
            float og = fast_sigmoid(ob);
            float gg = fast_tanh(gb);
            float pc = prevc[(size_t)row * SDIM + st];
            float nc = pc * fg + gg * ig;
            float nh = fast_tanh(nc) * og;
            outh[(size_t)row * SDIM + st] = nh;
            outc[(size_t)row * SDIM + st] = nc;
        }
    }
}

extern "C" void kernel_launch(void* const* d_in, const int* in_sizes, int n_in,
                              void* d_out, int out_size, void* d_ws, size_t ws_size,
                              hipStream_t stream) {
    const float* x     = (const float*)d_in[0];
    const float* prevh = (const float*)d_in[1];
    const float* prevc = (const float*)d_in[2];
    const float* Wx    = (const float*)d_in[3];
    const float* bx    = (const float*)d_in[4];
    const float* Wh    = (const float*)d_in[5];

    __hip_bfloat16* Abf = (__hip_bfloat16*)d_ws;
    __hip_bfloat16* Wt  = Abf + (size_t)BATCH * KDIM;   // +32MB

    float* outh = (float*)d_out;
    float* outc = outh + (size_t)BATCH * SDIM;

    // merged conversions: 8192 A-blocks + 2048 W-blocks
    hipLaunchKernelGGL(convAW, dim3(10240), dim3(256), 0, stream,
                       x, prevh, Wx, Wh, Abf, Wt);
    hipLaunchKernelGGL(lstm_gemm, dim3(512), dim3(512), 0, stream,
                       Abf, Wt, bx, prevc, outh, outc);
}

// Round 15
// 152.850 us; speedup vs baseline: 1.2488x; 1.0202x over previous
//
#include <hip/hip_runtime.h>
#include <hip/hip_bf16.h>

// LSTM cell fused kernel for MI355X (gfx950) — round 15: round-14 minus
// s_setprio (T5 is measured-negative on lockstep 2-barrier GEMM structures,
// m190). All sync primitives (barriers, vmcnt asm, sched_barrier pins)
// unchanged — the pins are load-bearing: they keep SB(t+2) below the
// mid-barrier and next-tile ds_reads below the end-barrier (raw s_barrier
// has no IR memory-fence semantics; without pins the compiler may hoist
// LDS-writing gloads / ds_reads across it -> cross-wave race).
//
// stacked = [x|prevh] @ [Wx;Wh] + bx -> gates -> nexth, nextc
// GEMM: M=8192, N=4096 (4 gates x 1024 states), K=2048, bf16 16x16x32 MFMA.
//
// ws layout: A_bf16 [8192][2048] (32MB) | Wt_bf16 [4096 perm][2048] (16MB)

#define BATCH   8192
#define SDIM    1024
#define KDIM    2048
#define NT      32      // K-tiles of 64

typedef __attribute__((ext_vector_type(8))) short s16x8;
typedef __attribute__((ext_vector_type(4))) float f32x4;

__device__ __forceinline__ void gload16(const void* g, void* l) {
    __builtin_amdgcn_global_load_lds((const __attribute__((address_space(1))) void*)g,
                                     (__attribute__((address_space(3))) void*)l,
                                     16, 0, 0);
}

__device__ __forceinline__ float fast_sigmoid(float x) {
    return 1.0f / (1.0f + __expf(-x));
}
__device__ __forceinline__ float fast_tanh(float v) {
    float a = fabsf(v);
    float e = __expf(-2.0f * a);
    float t = (1.0f - e) / (1.0f + e);
    return copysignf(t, v);
}

// ---------------- merged conversions ----------------------------------------
// blocks [0, 8192):  A = [x | prevh] -> bf16 [8192][2048]   (16B loads/stores)
// blocks [8192, 10240): Wt[np][k] = W[k][n], np = (s>>4)*64 + g*16 + (s&15)
//   via 64k x 64n LDS transpose tile; 16B (8-k-run) stores.
__global__ __launch_bounds__(256) void convAW(
    const float* __restrict__ x,  const float* __restrict__ h,
    const float* __restrict__ Wx, const float* __restrict__ Wh,
    __hip_bfloat16* __restrict__ A, __hip_bfloat16* __restrict__ Wt)
{
    __shared__ float tile[64][68];
    if (blockIdx.x < 8192) {
        int t = blockIdx.x * 256 + threadIdx.x;
        int e = t << 3;
        int b = e >> 11;
        int k = e & 2047;
        const float* src = (k < 1024) ? (x + (size_t)b * 1024 + k)
                                      : (h + (size_t)b * 1024 + (k - 1024));
        float4 v0 = *(const float4*)(src);
        float4 v1 = *(const float4*)(src + 4);
        union { __hip_bfloat16 b[8]; s16x8 v; } u;
        u.b[0] = __float2bfloat16(v0.x); u.b[1] = __float2bfloat16(v0.y);
        u.b[2] = __float2bfloat16(v0.z); u.b[3] = __float2bfloat16(v0.w);
        u.b[4] = __float2bfloat16(v1.x); u.b[5] = __float2bfloat16(v1.y);
        u.b[6] = __float2bfloat16(v1.z); u.b[7] = __float2bfloat16(v1.w);
        *(s16x8*)(A + e) = u.v;
    } else {
        const int wb = blockIdx.x - 8192;   // 0..2047
        const int kt = wb & 31;             // 32 k-tiles of 64
        const int nt = wb >> 5;             // 64 n-tiles of 64
        const int k0 = kt * 64, n0 = nt * 64;
        const int t  = threadIdx.x;

        {
            int r = t >> 2;
            int c = (t & 3) * 16;
            int k = k0 + r;   // k0 is 64-aligned: row never straddles Wx/Wh
            const float* src = (k < 1024) ? (Wx + (size_t)k * 4096 + n0 + c)
                                          : (Wh + (size_t)(k - 1024) * 4096 + n0 + c);
#pragma unroll
            for (int jq = 0; jq < 4; ++jq)
                *(float4*)&tile[r][c + jq * 4] = *(const float4*)(src + jq * 4);
        }
        __syncthreads();

#pragma unroll
        for (int it = 0; it < 2; ++it) {
            int item = t + it * 256;
            int oct  = item >> 6;          // 0..7
            int nl   = item & 63;
            int n    = n0 + nl;
            int s    = n & 1023, g = n >> 10;
            int np   = (s >> 4) * 64 + g * 16 + (s & 15);
            union { __hip_bfloat16 b[8]; s16x8 v; } u;
#pragma unroll
            for (int e = 0; e < 8; ++e)
                u.b[e] = __float2bfloat16(tile[oct * 8 + e][nl]);
            *(s16x8*)(Wt + (size_t)np * 2048 + k0 + oct * 8) = u.v;
        }
    }
}

// ---------------- fused GEMM + gates (round-4 schedule, no setprio) ---------
// 256x256 tile, BK=64, 8 waves (2M x 4N); A ring 4 half-slots [0,64K),
// B ring [64K,128K), half (t,p) at slot 2*(t&1)+p. 2 barriers/tile:
//   region1: bf reads(8) + af-lo reads(8) + SA(t+1)x2; 32 MFMA kf-outer
//   mid-barrier (B(t) LDS reads retired)
//   region2: af-hi reads(8, reuse regs) + SB(t+2)x2; 32 MFMA; vmcnt(4); bar
// T2 swizzle both-sides (0 conflicts measured), XCD chunking,
// gate-permuted Wt -> lane-local epilogue.
__global__ __launch_bounds__(512, 2) void lstm_gemm(
    const __hip_bfloat16* __restrict__ A,    // [8192][2048]
    const __hip_bfloat16* __restrict__ Wt,   // [4096 perm][2048]
    const float* __restrict__ bx,            // [4096]
    const float* __restrict__ prevc,         // [8192][1024]
    float* __restrict__ outh,
    float* __restrict__ outc)
{
    __shared__ __align__(16) char lds[131072];

    const int tid  = threadIdx.x;
    const int lane = tid & 63;
    const int w    = tid >> 6;   // 0..7
    const int wr   = w >> 2;     // 0..1  A-half
    const int wc   = w & 3;      // 0..3  N quarter; B-half = wc>>1
    const int l15  = lane & 15;

    const int bid = blockIdx.x;
    const int xcd = bid & 7, j = bid >> 3;
    const int mt = (xcd >> 1) * 8 + (j & 7);     // 0..31
    const int nt = (xcd & 1) * 8 + (j >> 3);     // 0..15
    const int m0 = mt * 256, n0 = nt * 256, S0 = nt * 64;

    const int scol = ((lane & 7) ^ (lane >> 3)) << 3;   // elems
    const __hip_bfloat16* Ag = A  + (size_t)m0 * KDIM;
    const __hip_bfloat16* Bg = Wt + (size_t)n0 * KDIM;

    auto SA = [&](int tt, int p) {
        char* dst = lds + (2 * (tt & 1) + p) * 16384 + w * 1024;
        const __hip_bfloat16* src =
            Ag + (size_t)(p * 128 + w * 8 + (lane >> 3)) * KDIM + tt * 64 + scol;
        gload16(src, dst);
        gload16(src + (size_t)64 * KDIM, dst + 8192);
    };
    auto SB = [&](int tt, int p) {
        char* dst = lds + 65536 + (2 * (tt & 1) + p) * 16384 + w * 1024;
        const __hip_bfloat16* src =
            Bg + (size_t)(p * 128 + w * 8 + (lane >> 3)) * KDIM + tt * 64 + scol;
        gload16(src, dst);
        gload16(src + (size_t)64 * KDIM, dst + 8192);
    };

    f32x4 acc[8][4];
#pragma unroll
    for (int m = 0; m < 8; ++m)
#pragma unroll
        for (int g = 0; g < 4; ++g)
            acc[m][g] = (f32x4)0.0f;

    SB(0, 0); SB(0, 1); SA(0, 0); SA(0, 1); SB(1, 0); SB(1, 1);
    asm volatile("s_waitcnt vmcnt(4)" ::: "memory");
    __builtin_amdgcn_s_barrier();
    __builtin_amdgcn_sched_barrier(0);

    const int swz0 = (((lane >> 4))     ^ (lane & 7)) << 4;
    const int swz1 = (((lane >> 4) | 4) ^ (lane & 7)) << 4;
    const int brow = (wc & 1) * 64;

    s16x8 af[4][2], bf[4][2];

    for (int t = 0; t < NT; ++t) {
        const char* as = lds + (2 * (t & 1) + wr) * 16384;
        const char* bs = lds + 65536 + (2 * (t & 1) + (wc >> 1)) * 16384;

        // ---- region 1: B reads, A-lo reads, SA(t+1); MFMA m0-3 x g0-3 ----
#pragma unroll
        for (int g = 0; g < 4; ++g) {
            bf[g][0] = *(const s16x8*)(bs + (brow + g * 16 + l15) * 128 + swz0);
            bf[g][1] = *(const s16x8*)(bs + (brow + g * 16 + l15) * 128 + swz1);
        }
#pragma unroll
        for (int m = 0; m < 4; ++m) {
            af[m][0] = *(const s16x8*)(as + (m * 16 + l15) * 128 + swz0);
            af[m][1] = *(const s16x8*)(as + (m * 16 + l15) * 128 + swz1);
        }
        if (t + 1 < NT) { SA(t + 1, 0); SA(t + 1, 1); }

#pragma unroll
        for (int kf = 0; kf < 2; ++kf)
#pragma unroll
            for (int m = 0; m < 4; ++m)
#pragma unroll
                for (int g = 0; g < 4; ++g)
                    acc[m][g] = __builtin_amdgcn_mfma_f32_16x16x32_bf16(
                        af[m][kf], bf[g][kf], acc[m][g], 0, 0, 0);

        __builtin_amdgcn_sched_barrier(0);
        __builtin_amdgcn_s_barrier();        // mid: all B(t) reads retired
        __builtin_amdgcn_sched_barrier(0);

        // ---- region 2: A-hi reads (reuse af), SB(t+2); MFMA m4-7 x g0-3 ----
#pragma unroll
        for (int m = 0; m < 4; ++m) {
            af[m][0] = *(const s16x8*)(as + ((m + 4) * 16 + l15) * 128 + swz0);
            af[m][1] = *(const s16x8*)(as + ((m + 4) * 16 + l15) * 128 + swz1);
        }
        if (t + 2 < NT) { SB(t + 2, 0); SB(t + 2, 1); }

#pragma unroll
        for (int kf = 0; kf < 2; ++kf)
#pragma unroll
            for (int m = 0; m < 4; ++m)
#pragma unroll
                for (int g = 0; g < 4; ++g)
                    acc[m + 4][g] = __builtin_amdgcn_mfma_f32_16x16x32_bf16(
                        af[m][kf], bf[g][kf], acc[m + 4][g], 0, 0, 0);

        __builtin_amdgcn_sched_barrier(0);
        if (t + 2 < NT) {
            asm volatile("s_waitcnt vmcnt(4)" ::: "memory");
        } else {
            asm volatile("s_waitcnt vmcnt(0)" ::: "memory");
        }
        __builtin_amdgcn_s_barrier();        // end: tile t+1 slots published
        __builtin_amdgcn_sched_barrier(0);
    }

    // ---- fused epilogue: 4 gates lane-local ----
    const int st  = S0 + wc * 16 + l15;
    const float b_i = bx[st];
    const float b_f = bx[1024 + st];
    const float b_o = bx[2048 + st];
    const float b_g = bx[3072 + st];
    const int rbase = m0 + wr * 128 + (lane >> 4) * 4;

#pragma unroll
    for (int m = 0; m < 8; ++m) {
#pragma unroll
        for (int q = 0; q < 4; ++q) {
            int row = rbase + m * 16 + q;
            float ib = acc[m][0][q] + b_i;
            float fb = acc[m][1][q] + b_f;
            float ob = acc[m][2][q] + b_o;
            float gb = acc[m][3][q] + b_g;
            float ig = fast_sigmoid(ib);
            float fg = fast_sigmoid(fb);
            float og = fast_sigmoid(ob);
            float gg = fast_tanh(gb);
            float pc = prevc[(size_t)row * SDIM + st];
            float nc = pc * fg + gg * ig;
            float nh = fast_tanh(nc) * og;
            outh[(size_t)row * SDIM + st] = nh;
            outc[(size_t)row * SDIM + st] = nc;
        }
    }
}

extern "C" void kernel_launch(void* const* d_in, const int* in_sizes, int n_in,
                              void* d_out, int out_size, void* d_ws, size_t ws_size,
                              hipStream_t stream) {
    const float* x     = (const float*)d_in[0];
    const float* prevh = (const float*)d_in[1];
    const float* prevc = (const float*)d_in[2];
    const float* Wx    = (const float*)d_in[3];
    const float* bx    = (const float*)d_in[4];
    const float* Wh    = (const float*)d_in[5];

    __hip_bfloat16* Abf = (__hip_bfloat16*)d_ws;
    __hip_bfloat16* Wt  = Abf + (size_t)BATCH * KDIM;   // +32MB

    float* outh = (float*)d_out;
    float* outc = outh + (size_t)BATCH * SDIM;

    // merged conversions: 8192 A-blocks + 2048 W-blocks
    hipLaunchKernelGGL(convAW, dim3(10240), dim3(256), 0, stream,
                       x, prevh, Wx, Wh, Abf, Wt);
    hipLaunchKernelGGL(lstm_gemm, dim3(512), dim3(512), 0, stream,
                       Abf, Wt, bx, prevc, outh, outc);
}